// Round 5
// baseline (376.004 us; speedup 1.0000x reference)
//
#include <hip/hip_runtime.h>
#include <cstdint>

#define M_PTS 8192
#define N_QRY 8192
#define BATCH 4

typedef unsigned long long u64;

// ---------------- helpers ----------------
__device__ __forceinline__ float d2_exact(float qx, float qy, float qz, float q2, float4 p) {
#pragma clang fp contract(off)
  float dot = (qx * p.x + qy * p.y) + qz * p.z;   // reference op order, no fma
  return (q2 + p.w) - 2.0f * dot;
}

__device__ __forceinline__ unsigned flipf(float d) {
  unsigned u = __float_as_uint(d);
  return u ^ ((unsigned)((int)u >> 31) | 0x80000000u);   // order-preserving float->uint
}

__device__ __forceinline__ int lane_prefix(u64 m) {
  return __builtin_amdgcn_mbcnt_hi((unsigned)(m >> 32),
         __builtin_amdgcn_mbcnt_lo((unsigned)m, 0));
}

__device__ __forceinline__ void ld_lds16(const float4* g, float4* l) {
  __builtin_amdgcn_global_load_lds((const __attribute__((address_space(1))) void*)g,
                                   (__attribute__((address_space(3))) void*)l, 16, 0, 0);
}

// pack (a,b) to 2xfp16 with round-toward-zero (v_cvt_pkrtz_f16_f32)
typedef __fp16 hw2_t __attribute__((ext_vector_type(2)));
__device__ __forceinline__ unsigned pack_rtz(float a, float b) {
  union { hw2_t v; unsigned u; } cu;
  cu.v = __builtin_amdgcn_cvt_pkrtz(a, b);
  return cu.u;
}

// smallest fp16 >= x (round-up conversion)
__device__ __forceinline__ _Float16 f16_ru(float x) {
  _Float16 h = (_Float16)x;
  if ((float)h < x) {
    union { _Float16 h; unsigned short s; } u; u.h = h;
    u.s = (u.s & 0x8000) ? (unsigned short)(u.s - 1) : (unsigned short)(u.s + 1);
    h = u.h;
  }
  return h;
}

__device__ __forceinline__ _Float16 h_from_u16(unsigned short s) {
  union { unsigned short s; _Float16 h; } u; u.s = s;
  return u.h;
}

// 16th smallest of the 64 lane values via cross-lane bitonic sort (verified R0-R4)
__device__ __forceinline__ float rank16(float v, int lane) {
#pragma unroll
  for (int k = 2; k <= 64; k <<= 1) {
#pragma unroll
    for (int j = k >> 1; j >= 1; j >>= 1) {
      float pv = __shfl_xor(v, j);
      bool keepmin = (((lane & k) == 0) == ((lane & j) == 0));
      float lo = fminf(v, pv), hi = fmaxf(v, pv);
      v = keepmin ? lo : hi;
    }
  }
  return __shfl(v, 15);
}

// ---------------- K0a: pack (x, y, z, x^2+y^2+z^2) ----------------
__global__ void pack_pts(const float* __restrict__ src, float4* __restrict__ dst, int total) {
#pragma clang fp contract(off)
  int i = blockIdx.x * 256 + threadIdx.x;
  if (i >= total) return;
  int b = i >> 13, m = i & (M_PTS - 1);
  const float* s = src + (size_t)b * 3 * M_PTS;
  float x = s[m], y = s[M_PTS + m], z = s[2 * M_PTS + m];
  float ss = (x * x + y * y) + z * z;   // matches jnp.sum(pts**2, axis=1) order
  dst[i] = make_float4(x, y, z, ss);
}

// ---------------- K0b: transpose local_feat (B,64,M) -> (B,M,64) ----------------
__global__ void transpose_lf(const float* __restrict__ lf, float* __restrict__ lfT) {
  __shared__ float tile[64][65];
  int bb = blockIdx.x >> 7;
  int m0 = (blockIdx.x & 127) << 6;
  int tm = threadIdx.x & 63;
  int tc = threadIdx.x >> 6;
  const float* src = lf + (size_t)bb * 64 * M_PTS;
#pragma unroll
  for (int i = 0; i < 16; i++) {
    int ch = i * 4 + tc;
    tile[ch][tm] = src[(size_t)ch * M_PTS + m0 + tm];
  }
  __syncthreads();
  float* dst = lfT + ((size_t)bb * M_PTS + m0) * 64;
#pragma unroll
  for (int i = 0; i < 16; i++) {
    int mm = i * 4 + tc;
    dst[(size_t)mm * 64 + tm] = tile[tm][mm];
  }
}

// ---------------- K1: exact KNN top-16 ----------------
// 512 threads (8 waves) share the staged chunk; 2 queries per wave.
// Hot key: e = fma(-2qx,px, fma(-2qy,py, fma(-2qz,pz, pw))) = d2 - q2 (ordering-equiv).
// (eA,eB) packed fp16 RTZ in ePk[64] (static indices -> pure VGPR, no scratch).
// tau = rank16 of fp32 lane-mins + R4-verified margin; survivors exact-rescored and
// selected by a 128-key bitonic sort on (flipf(exact_d2), idx) -> top-16 sorted,
// lower-index tie-break = top_k stability. Bit-identical output to R4.
__global__ void __launch_bounds__(512, 4) knn_kernel(const float4* __restrict__ pp,
                                                     const float4* __restrict__ qp,
                                                     int* __restrict__ knn_out) {
  __shared__ float4 spts[2][1024];       // double-buffered 16 KB chunks
  __shared__ unsigned cand[16][128];     // per-query candidate indices (8 KB)
  const int tid = threadIdx.x;
  const int lane = tid & 63;
  const int wave = tid >> 6;                      // 0..7
  const int b = blockIdx.x >> 9;                  // 512 blocks per batch
  const int qa = blockIdx.x * 16 + wave * 2;      // this wave's two queries
  const float4* pb = pp + ((size_t)b << 13);

  const float4 A4 = qp[qa];
  const float4 B4 = qp[qa + 1];
  const float axA = -2.0f * A4.x, ayA = -2.0f * A4.y, azA = -2.0f * A4.z;
  const float axB = -2.0f * B4.x, ayB = -2.0f * B4.y, azB = -2.0f * B4.z;

  unsigned ePk[64];                      // packed (eA,eB) fp16, one half (4096 pts) at a time
  int cntA = 0, cntB = 0;
  unsigned* cqA = cand[wave * 2 + 0];
  unsigned* cqB = cand[wave * 2 + 1];

  auto issue = [&](int c) {
#pragma unroll
    for (int i = 0; i < 2; i++) {
      const float4* g = pb + c * 1024 + wave * 128 + i * 64 + lane;   // per-lane global
      ld_lds16(g, &spts[c & 1][wave * 128 + i * 64]);                 // uniform LDS base
    }
  };

  issue(0);
  __syncthreads();                       // drains vmcnt -> chunk 0 visible to all waves

#pragma unroll
  for (int h = 0; h < 2; h++) {
    float mnA = 3.402823466e38f, mnB = 3.402823466e38f;
#pragma unroll
    for (int cc = 0; cc < 4; cc++) {
      const int c = h * 4 + cc;
      if (c + 1 < 8) issue(c + 1);       // prefetch; drains at this iteration's barrier
      const float4* buf = spts[c & 1];
#pragma unroll
      for (int j = 0; j < 16; j++) {
        float4 p = buf[j * 64 + lane];
        float ea = __builtin_fmaf(axA, p.x, __builtin_fmaf(ayA, p.y,
                   __builtin_fmaf(azA, p.z, p.w)));
        float eb = __builtin_fmaf(axB, p.x, __builtin_fmaf(ayB, p.y,
                   __builtin_fmaf(azB, p.z, p.w)));
        mnA = fminf(mnA, ea);
        mnB = fminf(mnB, eb);
        ePk[cc * 16 + j] = pack_rtz(ea, eb);   // static index: cc,j compile-time
      }
      if (cc == 3) {                     // end of half: select candidates (registers only)
        float t0A = rank16(mnA, lane);
        float t0B = rank16(mnB, lane);
        _Float16 thA = f16_ru(t0A + 0.01f + fabsf(t0A) * 1.2e-3f);
        _Float16 thB = f16_ru(t0B + 0.01f + fabsf(t0B) * 1.2e-3f);
#pragma unroll
        for (int r = 0; r < 64; r++) {
          unsigned pk = ePk[r];
          bool pA = h_from_u16((unsigned short)(pk & 0xffff)) <= thA;
          bool pB = h_from_u16((unsigned short)(pk >> 16)) <= thB;
          u64 mA = __ballot(pA);
          u64 mB = __ballot(pB);
          unsigned pidx = (unsigned)(h * 4096 + (r >> 4) * 1024 + (r & 15) * 64 + lane);
          if (mA) {
            int pos = cntA + lane_prefix(mA);
            if (pA && pos < 128) cqA[pos] = pidx;
            cntA += __popcll(mA);
          }
          if (mB) {
            int pos = cntB + lane_prefix(mB);
            if (pB && pos < 128) cqB[pos] = pidx;
            cntB += __popcll(mB);
          }
        }
      }
      __syncthreads();
    }
  }

  // finalize: exact-rescore + full 128-key bitonic sort (ascending by (d2,idx))
  auto finalize = [&](const unsigned* cq, int cnt, int gq,
                      float qx, float qy, float qz, float q2) {
    int E = cnt < 128 ? cnt : 128;            // E >= 32 guaranteed, ~40-70 typical
    unsigned i0 = cq[lane];
    unsigned i1 = cq[64 + lane];
    i0 = (lane < E) ? i0 : 0u;
    i1 = (lane + 64 < E) ? i1 : 0u;
    float4 p0 = pb[i0];                       // parallel L2-hit loads
    float4 p1 = pb[i1];
    u64 k0 = (lane < E)
        ? (((u64)flipf(d2_exact(qx, qy, qz, q2, p0)) << 32) | i0) : ~0ull;
    u64 k1 = (lane + 64 < E)
        ? (((u64)flipf(d2_exact(qx, qy, qz, q2, p1)) << 32) | i1) : ~0ull;
    // bitonic sort over idx = reg*64 + lane (reg is bit 6)
#pragma unroll
    for (int k = 2; k <= 128; k <<= 1) {
#pragma unroll
      for (int j = k >> 1; j >= 1; j >>= 1) {
        if (j == 64) {                        // only at k=128: cross-reg, ascending
          u64 lo = k0 < k1 ? k0 : k1;
          u64 hi = k0 < k1 ? k1 : k0;
          k0 = lo; k1 = hi;
        } else {
          u64 o0 = __shfl_xor(k0, j);
          u64 o1 = __shfl_xor(k1, j);
          bool up0 = ((lane & k) == 0);
          bool up1 = (((lane + 64) & k) == 0);
          bool sel0 = (((lane & j) == 0) == up0);
          bool sel1 = (((lane & j) == 0) == up1);
          k0 = sel0 ? (k0 < o0 ? k0 : o0) : (k0 > o0 ? k0 : o0);
          k1 = sel1 ? (k1 < o1 ? k1 : o1) : (k1 > o1 ? k1 : o1);
        }
      }
    }
    if (lane < 16) knn_out[(size_t)gq * 16 + lane] = (int)(unsigned)k0;
  };

  finalize(cqA, cntA, qa,     A4.x, A4.y, A4.z, A4.w);
  finalize(cqB, cntB, qa + 1, B4.x, B4.y, B4.z, B4.w);
}

// ---------------- K2: fused feature pipeline, ONE query per wave ----------------
__global__ void __launch_bounds__(256, 4) feat_kernel(
    const float4* __restrict__ pp, const float4* __restrict__ qp,
    const int* __restrict__ knn, const float* __restrict__ lfT,
    const float* __restrict__ w0, const float* __restrict__ b0,
    const float* __restrict__ g0, const float* __restrict__ be0,
    const float* __restrict__ m0, const float* __restrict__ v0,
    const float* __restrict__ w1, const float* __restrict__ b1,
    const float* __restrict__ g1, const float* __restrict__ be1,
    const float* __restrict__ m1, const float* __restrict__ v1,
    const float* __restrict__ w2, const float* __restrict__ b2,
    float* __restrict__ out) {
  __shared__ float4 relbuf[4][16];
  __shared__ float4 f0v[4][64];
  __shared__ float outbuf[4][65];      // [query][channel], pad
  const int tid = threadIdx.x;
  const int lane = tid & 63;
  const int wave = tid >> 6;
  const int gq = blockIdx.x * 4 + wave;
  const int b = gq >> 13;

  // BN folds (inline; fp order matches R0's fold_kernel — verified R1-R4)
  const float inv0 = g0[lane] / sqrtf(v0[lane] + 1e-5f);
  const float w00 = w0[lane * 3 + 0] * inv0;
  const float w01 = w0[lane * 3 + 1] * inv0;
  const float w02 = w0[lane * 3 + 2] * inv0;
  const float bb0 = (b0[lane] - m0[lane]) * inv0 + be0[lane];
  const float inv1 = g1[lane] / sqrtf(v1[lane] + 1e-5f);
  const float bb1 = (b1[lane] - m1[lane]) * inv1 + be1[lane];

  float w1s[64];
#pragma unroll
  for (int i = 0; i < 16; i++) {
    float4 t = ((const float4*)(w1 + (size_t)lane * 64))[i];
    w1s[i * 4 + 0] = t.x; w1s[i * 4 + 1] = t.y;
    w1s[i * 4 + 2] = t.z; w1s[i * 4 + 3] = t.w;
  }
  const float w2a = w2[lane], w2b = w2[64 + lane];
  const float bias2 = b2[0];
  const float4* pb = pp + ((size_t)b << 13);
  const float* lfb = lfT + (((size_t)b << 13)) * 64;

  const float4 q4 = qp[gq];
  int nk = knn[(size_t)gq * 16 + (lane & 15)];
  // issue patch-feature gathers early (hide HBM/L2 latency behind conv work)
  int i0 = __shfl(nk, 0), i1 = __shfl(nk, 1), i2 = __shfl(nk, 2), i3 = __shfl(nk, 3);
  float p0 = lfb[(size_t)i0 * 64 + lane];
  float p1 = lfb[(size_t)i1 * 64 + lane];
  float p2 = lfb[(size_t)i2 * 64 + lane];
  float p3 = lfb[(size_t)i3 * 64 + lane];

  float4 pk = pb[nk];
  if (lane < 16)
    relbuf[wave][lane] = make_float4(pk.x - q4.x, pk.y - q4.y, pk.z - q4.z, 0.0f);
  // wave-local RAW: same-wave DS ordering suffices, no barrier

  float g = 0.0f, f0 = 0, f1 = 0, f2 = 0, f3 = 0;
#pragma unroll
  for (int k = 0; k < 16; k++) {
    float4 r = relbuf[wave][k];
    float y = fmaxf(0.0f, w00 * r.x + w01 * r.y + w02 * r.z + bb0);
    g = fmaxf(g, y);
    if (k == 0) f0 = y; else if (k == 1) f1 = y;
    else if (k == 2) f2 = y; else if (k == 3) f3 = y;
  }
  f0v[wave][lane] = make_float4(f0, f1, f2, f3);

  float a0 = 0, a1 = 0, a2 = 0, a3 = 0;
#pragma unroll
  for (int c2 = 0; c2 < 64; c2++) {
    float w = w1s[c2];                 // register (compile-time index)
    float4 fb = f0v[wave][c2];         // LDS broadcast
    a0 = fmaf(w, fb.x, a0); a1 = fmaf(w, fb.y, a1);
    a2 = fmaf(w, fb.z, a2); a3 = fmaf(w, fb.w, a3);
  }
  float r0 = fmaxf(0.0f, fmaf(a0, inv1, bb1));
  float r1 = fmaxf(0.0f, fmaf(a1, inv1, bb1));
  float r2 = fmaxf(0.0f, fmaf(a2, inv1, bb1));
  float r3 = fmaxf(0.0f, fmaf(a3, inv1, bb1));

  float s0 = w2a * r0, s1 = w2a * r1, s2 = w2a * r2, s3 = w2a * r3, tg = w2b * g;
#pragma unroll
  for (int j = 1; j < 64; j <<= 1) {
    s0 += __shfl_xor(s0, j);
    s1 += __shfl_xor(s1, j);
    s2 += __shfl_xor(s2, j);
    s3 += __shfl_xor(s3, j);
    tg += __shfl_xor(tg, j);
  }
  float wk0 = 1.0f / (1.0f + __expf(-(s0 + tg + bias2)));
  float wk1 = 1.0f / (1.0f + __expf(-(s1 + tg + bias2)));
  float wk2 = 1.0f / (1.0f + __expf(-(s2 + tg + bias2)));
  float wk3 = 1.0f / (1.0f + __expf(-(s3 + tg + bias2)));

  float oc = ((1.0f - wk0) * r0 + wk0 * p0)
           + ((1.0f - wk1) * r1 + wk1 * p1)
           + ((1.0f - wk2) * r2 + wk2 * p2)
           + ((1.0f - wk3) * r3 + wk3 * p3);
  outbuf[wave][lane] = oc;
  __syncthreads();

  // coalesced-ish output: thread t -> channel c=t>>2, query j=t&3 (16B segments/channel)
  int c = tid >> 2, j = tid & 3;
  int n0 = (blockIdx.x * 4) & (N_QRY - 1);
  out[(((size_t)(b * 64 + c)) << 13) + n0 + j] = outbuf[j][c];
}

extern "C" void kernel_launch(void* const* d_in, const int* in_sizes, int n_in,
                              void* d_out, int out_size, void* d_ws, size_t ws_size,
                              hipStream_t stream) {
  (void)in_sizes; (void)n_in; (void)out_size; (void)ws_size;
  const float* original_pts = (const float*)d_in[0];
  const float* query_pts   = (const float*)d_in[1];
  const float* local_feat  = (const float*)d_in[2];
  const float* w0 = (const float*)d_in[3];
  const float* b0 = (const float*)d_in[4];
  const float* g0 = (const float*)d_in[5];
  const float* be0 = (const float*)d_in[6];
  const float* m0 = (const float*)d_in[7];
  const float* v0 = (const float*)d_in[8];
  const float* w1 = (const float*)d_in[9];
  const float* b1 = (const float*)d_in[10];
  const float* g1 = (const float*)d_in[11];
  const float* be1 = (const float*)d_in[12];
  const float* m1 = (const float*)d_in[13];
  const float* v1 = (const float*)d_in[14];
  const float* w2 = (const float*)d_in[15];
  const float* b2 = (const float*)d_in[16];
  float* out = (float*)d_out;

  // workspace layout (16B aligned), total ~11.5 MB
  char* ws = (char*)d_ws;
  float4* pp  = (float4*)(ws);                 // 512 KB
  float4* qp  = (float4*)(ws + 524288);        // 512 KB
  float*  lfT = (float*)(ws + 1048576);        // 8 MB
  int*    knn = (int*)(ws + 9437184);          // 2 MB

  pack_pts<<<128, 256, 0, stream>>>(original_pts, pp, BATCH * M_PTS);
  pack_pts<<<128, 256, 0, stream>>>(query_pts, qp, BATCH * N_QRY);
  transpose_lf<<<512, 256, 0, stream>>>(local_feat, lfT);
  knn_kernel<<<2048, 512, 0, stream>>>(pp, qp, knn);
  feat_kernel<<<8192, 256, 0, stream>>>(pp, qp, knn, lfT,
                                        w0, b0, g0, be0, m0, v0,
                                        w1, b1, g1, be1, m1, v1,
                                        w2, b2, out);
}

// Round 6
// 326.249 us; speedup vs baseline: 1.1525x; 1.1525x over previous
//
#include <hip/hip_runtime.h>
#include <cstdint>

#define M_PTS 8192
#define N_QRY 8192
#define BATCH 4

typedef unsigned long long u64;

// ---------------- helpers ----------------
__device__ __forceinline__ float d2_exact(float qx, float qy, float qz, float q2, float4 p) {
#pragma clang fp contract(off)
  float dot = (qx * p.x + qy * p.y) + qz * p.z;   // reference op order, no fma
  return (q2 + p.w) - 2.0f * dot;
}

__device__ __forceinline__ unsigned flipf(float d) {
  unsigned u = __float_as_uint(d);
  return u ^ ((unsigned)((int)u >> 31) | 0x80000000u);   // order-preserving float->uint
}

__device__ __forceinline__ int lane_prefix(u64 m) {
  return __builtin_amdgcn_mbcnt_hi((unsigned)(m >> 32),
         __builtin_amdgcn_mbcnt_lo((unsigned)m, 0));
}

__device__ __forceinline__ void ld_lds16(const float4* g, float4* l) {
  __builtin_amdgcn_global_load_lds((const __attribute__((address_space(1))) void*)g,
                                   (__attribute__((address_space(3))) void*)l, 16, 0, 0);
}

// pack (a,b) to 2xfp16 with round-toward-zero (v_cvt_pkrtz_f16_f32)
typedef __fp16 hw2_t __attribute__((ext_vector_type(2)));
__device__ __forceinline__ unsigned pack_rtz(float a, float b) {
  union { hw2_t v; unsigned u; } cu;
  cu.v = __builtin_amdgcn_cvt_pkrtz(a, b);
  return cu.u;
}

// smallest fp16 >= x (round-up conversion)
__device__ __forceinline__ _Float16 f16_ru(float x) {
  _Float16 h = (_Float16)x;
  if ((float)h < x) {
    union { _Float16 h; unsigned short s; } u; u.h = h;
    u.s = (u.s & 0x8000) ? (unsigned short)(u.s - 1) : (unsigned short)(u.s + 1);
    h = u.h;
  }
  return h;
}

__device__ __forceinline__ _Float16 h_from_u16(unsigned short s) {
  union { unsigned short s; _Float16 h; } u; u.s = s;
  return u.h;
}

// 16th smallest of the 64 lane values via cross-lane bitonic sort (verified R0-R5)
__device__ __forceinline__ float rank16(float v, int lane) {
#pragma unroll
  for (int k = 2; k <= 64; k <<= 1) {
#pragma unroll
    for (int j = k >> 1; j >= 1; j >>= 1) {
      float pv = __shfl_xor(v, j);
      bool keepmin = (((lane & k) == 0) == ((lane & j) == 0));
      float lo = fminf(v, pv), hi = fmaxf(v, pv);
      v = keepmin ? lo : hi;
    }
  }
  return __shfl(v, 15);
}

// ---------------- K0a: pack (x, y, z, x^2+y^2+z^2) ----------------
__global__ void pack_pts(const float* __restrict__ src, float4* __restrict__ dst, int total) {
#pragma clang fp contract(off)
  int i = blockIdx.x * 256 + threadIdx.x;
  if (i >= total) return;
  int b = i >> 13, m = i & (M_PTS - 1);
  const float* s = src + (size_t)b * 3 * M_PTS;
  float x = s[m], y = s[M_PTS + m], z = s[2 * M_PTS + m];
  float ss = (x * x + y * y) + z * z;   // matches jnp.sum(pts**2, axis=1) order
  dst[i] = make_float4(x, y, z, ss);
}

// ---------------- K0b: transpose local_feat (B,64,M) -> (B,M,64) ----------------
__global__ void transpose_lf(const float* __restrict__ lf, float* __restrict__ lfT) {
  __shared__ float tile[64][65];
  int bb = blockIdx.x >> 7;
  int m0 = (blockIdx.x & 127) << 6;
  int tm = threadIdx.x & 63;
  int tc = threadIdx.x >> 6;
  const float* src = lf + (size_t)bb * 64 * M_PTS;
#pragma unroll
  for (int i = 0; i < 16; i++) {
    int ch = i * 4 + tc;
    tile[ch][tm] = src[(size_t)ch * M_PTS + m0 + tm];
  }
  __syncthreads();
  float* dst = lfT + ((size_t)bb * M_PTS + m0) * 64;
#pragma unroll
  for (int i = 0; i < 16; i++) {
    int mm = i * 4 + tc;
    dst[(size_t)mm * 64 + tm] = tile[tm][mm];
  }
}

// ---------------- K1: exact KNN top-16 ----------------
// 512 threads (8 waves) share the staged chunk; 2 queries per wave.
// __launch_bounds__(512,2): VGPR cap 128 so ePk[64] stays in registers.
// (R5's (512,4) capped VGPR at 64 -> whole e-cache spilled -> 647 MB HBM traffic.)
// Hot key: e = fma(-2qx,px, fma(-2qy,py, fma(-2qz,pz, pw))) = d2 - q2 (ordering-equiv).
// tau = rank16 of fp32 lane-mins + verified margin; survivors exact-rescored and
// selected by a 128-key bitonic sort on (flipf(exact_d2), idx) -> top-16 sorted,
// lower-index tie-break = top_k stability. Output bit-identical to R4/R5.
__global__ void __launch_bounds__(512, 2) knn_kernel(const float4* __restrict__ pp,
                                                     const float4* __restrict__ qp,
                                                     int* __restrict__ knn_out) {
  __shared__ float4 spts[2][1024];       // double-buffered 16 KB chunks
  __shared__ unsigned cand[16][128];     // per-query candidate indices (8 KB)
  const int tid = threadIdx.x;
  const int lane = tid & 63;
  const int wave = tid >> 6;                      // 0..7
  const int b = blockIdx.x >> 9;                  // 512 blocks per batch
  const int qa = blockIdx.x * 16 + wave * 2;      // this wave's two queries
  const float4* pb = pp + ((size_t)b << 13);

  const float4 A4 = qp[qa];
  const float4 B4 = qp[qa + 1];
  const float axA = -2.0f * A4.x, ayA = -2.0f * A4.y, azA = -2.0f * A4.z;
  const float axB = -2.0f * B4.x, ayB = -2.0f * B4.y, azB = -2.0f * B4.z;

  unsigned ePk[64];                      // packed (eA,eB) fp16, one half (4096 pts) at a time
  int cntA = 0, cntB = 0;
  unsigned* cqA = cand[wave * 2 + 0];
  unsigned* cqB = cand[wave * 2 + 1];

  auto issue = [&](int c) {
#pragma unroll
    for (int i = 0; i < 2; i++) {
      const float4* g = pb + c * 1024 + wave * 128 + i * 64 + lane;   // per-lane global
      ld_lds16(g, &spts[c & 1][wave * 128 + i * 64]);                 // uniform LDS base
    }
  };

  issue(0);
  __syncthreads();                       // drains vmcnt -> chunk 0 visible to all waves

#pragma unroll
  for (int h = 0; h < 2; h++) {
    float mnA = 3.402823466e38f, mnB = 3.402823466e38f;
#pragma unroll
    for (int cc = 0; cc < 4; cc++) {
      const int c = h * 4 + cc;
      if (c + 1 < 8) issue(c + 1);       // prefetch; drains at this iteration's barrier
      const float4* buf = spts[c & 1];
#pragma unroll
      for (int j = 0; j < 16; j++) {
        float4 p = buf[j * 64 + lane];
        float ea = __builtin_fmaf(axA, p.x, __builtin_fmaf(ayA, p.y,
                   __builtin_fmaf(azA, p.z, p.w)));
        float eb = __builtin_fmaf(axB, p.x, __builtin_fmaf(ayB, p.y,
                   __builtin_fmaf(azB, p.z, p.w)));
        mnA = fminf(mnA, ea);
        mnB = fminf(mnB, eb);
        ePk[cc * 16 + j] = pack_rtz(ea, eb);   // static index: cc,j compile-time
      }
      if (cc == 3) {                     // end of half: select candidates (registers only)
        float t0A = rank16(mnA, lane);
        float t0B = rank16(mnB, lane);
        _Float16 thA = f16_ru(t0A + 0.01f + fabsf(t0A) * 1.2e-3f);
        _Float16 thB = f16_ru(t0B + 0.01f + fabsf(t0B) * 1.2e-3f);
#pragma unroll
        for (int r = 0; r < 64; r++) {
          unsigned pk = ePk[r];
          bool pA = h_from_u16((unsigned short)(pk & 0xffff)) <= thA;
          bool pB = h_from_u16((unsigned short)(pk >> 16)) <= thB;
          u64 mA = __ballot(pA);
          u64 mB = __ballot(pB);
          unsigned pidx = (unsigned)(h * 4096 + (r >> 4) * 1024 + (r & 15) * 64 + lane);
          if (mA) {
            int pos = cntA + lane_prefix(mA);
            if (pA && pos < 128) cqA[pos] = pidx;
            cntA += __popcll(mA);
          }
          if (mB) {
            int pos = cntB + lane_prefix(mB);
            if (pB && pos < 128) cqB[pos] = pidx;
            cntB += __popcll(mB);
          }
        }
      }
      __syncthreads();
    }
  }

  // finalize: exact-rescore + full 128-key bitonic sort (ascending by (d2,idx))
  auto finalize = [&](const unsigned* cq, int cnt, int gq,
                      float qx, float qy, float qz, float q2) {
    int E = cnt < 128 ? cnt : 128;            // E >= 32 guaranteed, ~40-70 typical
    unsigned i0 = cq[lane];
    unsigned i1 = cq[64 + lane];
    i0 = (lane < E) ? i0 : 0u;
    i1 = (lane + 64 < E) ? i1 : 0u;
    float4 p0 = pb[i0];                       // parallel L2-hit loads
    float4 p1 = pb[i1];
    u64 k0 = (lane < E)
        ? (((u64)flipf(d2_exact(qx, qy, qz, q2, p0)) << 32) | i0) : ~0ull;
    u64 k1 = (lane + 64 < E)
        ? (((u64)flipf(d2_exact(qx, qy, qz, q2, p1)) << 32) | i1) : ~0ull;
    // bitonic sort over idx = reg*64 + lane (reg is bit 6)
#pragma unroll
    for (int k = 2; k <= 128; k <<= 1) {
#pragma unroll
      for (int j = k >> 1; j >= 1; j >>= 1) {
        if (j == 64) {                        // only at k=128: cross-reg, ascending
          u64 lo = k0 < k1 ? k0 : k1;
          u64 hi = k0 < k1 ? k1 : k0;
          k0 = lo; k1 = hi;
        } else {
          u64 o0 = __shfl_xor(k0, j);
          u64 o1 = __shfl_xor(k1, j);
          bool up0 = ((lane & k) == 0);
          bool up1 = (((lane + 64) & k) == 0);
          bool sel0 = (((lane & j) == 0) == up0);
          bool sel1 = (((lane & j) == 0) == up1);
          k0 = sel0 ? (k0 < o0 ? k0 : o0) : (k0 > o0 ? k0 : o0);
          k1 = sel1 ? (k1 < o1 ? k1 : o1) : (k1 > o1 ? k1 : o1);
        }
      }
    }
    if (lane < 16) knn_out[(size_t)gq * 16 + lane] = (int)(unsigned)k0;
  };

  finalize(cqA, cntA, qa,     A4.x, A4.y, A4.z, A4.w);
  finalize(cqB, cntB, qa + 1, B4.x, B4.y, B4.z, B4.w);
}

// ---------------- K2: fused feature pipeline, 16 queries per block (R2-verified) ----------------
__global__ void __launch_bounds__(256, 3) feat_kernel(
    const float4* __restrict__ pp, const float4* __restrict__ qp,
    const int* __restrict__ knn, const float* __restrict__ lfT,
    const float* __restrict__ w0, const float* __restrict__ b0,
    const float* __restrict__ g0, const float* __restrict__ be0,
    const float* __restrict__ m0, const float* __restrict__ v0,
    const float* __restrict__ w1, const float* __restrict__ b1,
    const float* __restrict__ g1, const float* __restrict__ be1,
    const float* __restrict__ m1, const float* __restrict__ v1,
    const float* __restrict__ w2, const float* __restrict__ b2,
    float* __restrict__ out) {
  __shared__ float4 relbuf[4][16];
  __shared__ float4 f0v[4][64];
  __shared__ float outbuf[64][17];     // +1 pad breaks write-phase bank conflicts
  const int tid = threadIdx.x;
  const int lane = tid & 63;
  const int wave = tid >> 6;
  const int gq0 = blockIdx.x * 16;
  const int b = gq0 >> 13;

  // BN folds (inline; fp order matches R0's fold_kernel)
  const float inv0 = g0[lane] / sqrtf(v0[lane] + 1e-5f);
  const float w00 = w0[lane * 3 + 0] * inv0;
  const float w01 = w0[lane * 3 + 1] * inv0;
  const float w02 = w0[lane * 3 + 2] * inv0;
  const float bb0 = (b0[lane] - m0[lane]) * inv0 + be0[lane];
  const float inv1 = g1[lane] / sqrtf(v1[lane] + 1e-5f);
  const float bb1 = (b1[lane] - m1[lane]) * inv1 + be1[lane];

  float w1s[64];
#pragma unroll
  for (int i = 0; i < 16; i++) {
    float4 t = ((const float4*)(w1 + (size_t)lane * 64))[i];
    w1s[i * 4 + 0] = t.x; w1s[i * 4 + 1] = t.y;
    w1s[i * 4 + 2] = t.z; w1s[i * 4 + 3] = t.w;
  }
  const float w2a = w2[lane], w2b = w2[64 + lane];
  const float bias2 = b2[0];
  const float4* pb = pp + ((size_t)b << 13);
  const float* lfb = lfT + (((size_t)b << 13)) * 64;

  for (int qi = 0; qi < 4; qi++) {
    const int gq = gq0 + wave * 4 + qi;
    const float4 q4 = qp[gq];
    int nk = knn[(size_t)gq * 16 + (lane & 15)];
    float4 pk = pb[nk];
    if (lane < 16)
      relbuf[wave][lane] = make_float4(pk.x - q4.x, pk.y - q4.y, pk.z - q4.z, 0.0f);
    // wave-local RAW: same-wave DS ordering suffices, no barrier

    float g = 0.0f, f0 = 0, f1 = 0, f2 = 0, f3 = 0;
#pragma unroll
    for (int k = 0; k < 16; k++) {
      float4 r = relbuf[wave][k];
      float y = fmaxf(0.0f, w00 * r.x + w01 * r.y + w02 * r.z + bb0);
      g = fmaxf(g, y);
      if (k == 0) f0 = y; else if (k == 1) f1 = y;
      else if (k == 2) f2 = y; else if (k == 3) f3 = y;
    }
    f0v[wave][lane] = make_float4(f0, f1, f2, f3);

    float a0 = 0, a1 = 0, a2 = 0, a3 = 0;
#pragma unroll
    for (int c2 = 0; c2 < 64; c2++) {
      float w = w1s[c2];                 // register (compile-time index)
      float4 fb = f0v[wave][c2];         // LDS broadcast
      a0 = fmaf(w, fb.x, a0); a1 = fmaf(w, fb.y, a1);
      a2 = fmaf(w, fb.z, a2); a3 = fmaf(w, fb.w, a3);
    }
    float r0 = fmaxf(0.0f, fmaf(a0, inv1, bb1));
    float r1 = fmaxf(0.0f, fmaf(a1, inv1, bb1));
    float r2 = fmaxf(0.0f, fmaf(a2, inv1, bb1));
    float r3 = fmaxf(0.0f, fmaf(a3, inv1, bb1));

    int i0 = __shfl(nk, 0), i1 = __shfl(nk, 1), i2 = __shfl(nk, 2), i3 = __shfl(nk, 3);
    float p0 = lfb[(size_t)i0 * 64 + lane];
    float p1 = lfb[(size_t)i1 * 64 + lane];
    float p2 = lfb[(size_t)i2 * 64 + lane];
    float p3 = lfb[(size_t)i3 * 64 + lane];

    float s0 = w2a * r0, s1 = w2a * r1, s2 = w2a * r2, s3 = w2a * r3, tg = w2b * g;
#pragma unroll
    for (int j = 1; j < 64; j <<= 1) {
      s0 += __shfl_xor(s0, j);
      s1 += __shfl_xor(s1, j);
      s2 += __shfl_xor(s2, j);
      s3 += __shfl_xor(s3, j);
      tg += __shfl_xor(tg, j);
    }
    float wk0 = 1.0f / (1.0f + __expf(-(s0 + tg + bias2)));
    float wk1 = 1.0f / (1.0f + __expf(-(s1 + tg + bias2)));
    float wk2 = 1.0f / (1.0f + __expf(-(s2 + tg + bias2)));
    float wk3 = 1.0f / (1.0f + __expf(-(s3 + tg + bias2)));

    float oc = ((1.0f - wk0) * r0 + wk0 * p0)
             + ((1.0f - wk1) * r1 + wk1 * p1)
             + ((1.0f - wk2) * r2 + wk2 * p2)
             + ((1.0f - wk3) * r3 + wk3 * p3);
    outbuf[lane][wave * 4 + qi] = oc;
  }
  __syncthreads();

  // coalesced output: thread t -> channel c = t>>2, 4 queries via float4
  int c = tid >> 2, j = tid & 3;
  float4 o4 = make_float4(outbuf[c][j * 4 + 0], outbuf[c][j * 4 + 1],
                          outbuf[c][j * 4 + 2], outbuf[c][j * 4 + 3]);
  *(float4*)(out + (((size_t)(b * 64 + c)) << 13) + (gq0 & (N_QRY - 1)) + j * 4) = o4;
}

extern "C" void kernel_launch(void* const* d_in, const int* in_sizes, int n_in,
                              void* d_out, int out_size, void* d_ws, size_t ws_size,
                              hipStream_t stream) {
  (void)in_sizes; (void)n_in; (void)out_size; (void)ws_size;
  const float* original_pts = (const float*)d_in[0];
  const float* query_pts   = (const float*)d_in[1];
  const float* local_feat  = (const float*)d_in[2];
  const float* w0 = (const float*)d_in[3];
  const float* b0 = (const float*)d_in[4];
  const float* g0 = (const float*)d_in[5];
  const float* be0 = (const float*)d_in[6];
  const float* m0 = (const float*)d_in[7];
  const float* v0 = (const float*)d_in[8];
  const float* w1 = (const float*)d_in[9];
  const float* b1 = (const float*)d_in[10];
  const float* g1 = (const float*)d_in[11];
  const float* be1 = (const float*)d_in[12];
  const float* m1 = (const float*)d_in[13];
  const float* v1 = (const float*)d_in[14];
  const float* w2 = (const float*)d_in[15];
  const float* b2 = (const float*)d_in[16];
  float* out = (float*)d_out;

  // workspace layout (16B aligned), total ~11.5 MB
  char* ws = (char*)d_ws;
  float4* pp  = (float4*)(ws);                 // 512 KB
  float4* qp  = (float4*)(ws + 524288);        // 512 KB
  float*  lfT = (float*)(ws + 1048576);        // 8 MB
  int*    knn = (int*)(ws + 9437184);          // 2 MB

  pack_pts<<<128, 256, 0, stream>>>(original_pts, pp, BATCH * M_PTS);
  pack_pts<<<128, 256, 0, stream>>>(query_pts, qp, BATCH * N_QRY);
  transpose_lf<<<512, 256, 0, stream>>>(local_feat, lfT);
  knn_kernel<<<2048, 512, 0, stream>>>(pp, qp, knn);
  feat_kernel<<<2048, 256, 0, stream>>>(pp, qp, knn, lfT,
                                        w0, b0, g0, be0, m0, v0,
                                        w1, b1, g1, be1, m1, v1,
                                        w2, b2, out);
}